// Round 6
// baseline (250.292 us; speedup 1.0000x reference)
//
#include <hip/hip_runtime.h>
#include <math.h>

// Sampler: B=256 rows, V=128256 vocab.
// out[b] = (T[b]==0) ? argmax(logits[b,:])
//                    : argmax(logits[b,:]/T[b] - log(-log1p(-noise[b,:])))
// Log-space Gumbel-max (softmax denom + row-max cancel), all in log2 so each
// log is one HW v_log_f32.
//
// R9 post-mortem: nt + guaranteed depth-3 = 245.5 (vs 248.0 at-use nt):
// depth-insensitive AGAIN, now on the nt path at ~3.5 TB/s.  Model: per-CU
// outstanding-line tracker -- BW = 256 * N * 64B / latency; N~64 at the
// measured 50/50 L3/HBM mix (~650-700cy blended) = 3.5-3.7 TB/s.  SW depth
// beyond tracker capacity queues in the TCP; adds nothing.
// R10: test whether the tracker is per-PATH.  The chip has a second VMEM
// load path: global_load_lds DMA (no VGPR writeback).  Hybrid streams:
// logits via VGPR-nt loads, noise via LDS-DMA (aux=NT), simultaneously.
//   - independent pools -> paths add (~3.5 + ~2.4 -> ~4.8 TB/s @ 50/50);
//   - shared pool -> exact null.
// Same R9 pipeline/counting: ISSUE pair = {VGPR-nt load, DMA}, vmcnt(6) ->
// 3 pairs in flight; 4-stage per-wave LDS ring (16KB/block); stage indices
// compile-time constants; consume's LDS read behind counted vmcnt +
// sched_barrier(0).  Greedy path: pure VGPR-nt (unchanged).

constexpr int TPB    = 256;
constexpr int CHUNKS = 8;
constexpr int WPB    = TPB / 64;   // 4 waves/block

typedef float v4f __attribute__((ext_vector_type(4)));

__device__ __forceinline__ void amax_comb(float v, int i, float& bv, int& bi) {
    // np.argmax semantics: strictly greater wins; ties -> lowest index
    if (v > bv || (v == bv && i < bi)) { bv = v; bi = i; }
}

// key = l*c - log2(-log1p(-u)), c = invT/ln2.  Abs err ~1e-6, far below
// top-1/top-2 Gumbel key gaps.  u==0 -> en=0 -> -inf -> key=+inf, matching
// reference probs/0 = +inf (first-index tie-break both sides).
__device__ __forceinline__ float gumbel_key(float l, float u, float c) {
    // u >= 0.125: 1-u exact on the 2^-24 uniform grid, |log2(1-u)| >= 0.19
    const float w   = 1.0f - u;
    const float enw = __log2f(w) * -0.693147180559945f;   // -log(1-u)
    // u < 0.125: en/u = 1 + u/2 + u^2/3 + ... (trunc err < 6e-6 rel)
    float p = 0.16666667f;
    p = fmaf(p, u, 0.2f);
    p = fmaf(p, u, 0.25f);
    p = fmaf(p, u, 0.33333333f);
    p = fmaf(p, u, 0.5f);
    p = fmaf(p, u, 1.0f);
    const float en = (u < 0.125f) ? p * u : enw;
    return fmaf(l, c, -__log2f(en));
}

// Counted wait: oldest loads retired, N newest still in flight.  The
// sched_barrier stops the compiler hoisting consumers above the wait.
#define WAITV(N)                                                        \
    asm volatile("s_waitcnt vmcnt(" #N ")" ::: "memory");               \
    __builtin_amdgcn_sched_barrier(0)

// Hybrid issue of batch J: logits -> VGPR via asm nt load (opaque, pinned);
// noise -> LDS stage ST via DMA (aux=2: NT).  Both increment vmcnt; vmcnt
// decrements in issue order, so pair counting is exact.
#define ISSUE_H(LD, J, ST)                                              \
    {                                                                   \
        const int fi = min(t + (J) * TPB, last);                        \
        asm volatile("global_load_dwordx4 %0, %1, off nt"               \
                     : "=&v"(LD) : "v"(lg4 + fi));                      \
        __builtin_amdgcn_global_load_lds((const void*)(nz4 + fi),       \
                                         (void*)&nbuf[ST][wave][0],     \
                                         16, 0, 2 /*NT*/);              \
        __builtin_amdgcn_sched_barrier(0);                              \
    }

// Consume batch JC: logits from VGPR (LC), noise from LDS stage ST.
#define CONS_H(LC, JC, ST)                                              \
    {                                                                   \
        const int f = t + (JC) * TPB;                                   \
        volatile const v4f* pU = &nbuf[ST][wave][lane];                 \
        const v4f u = *pU;                                              \
        if (f < V4c) {                                                  \
            const int base = (gbase + f) << 2;                          \
            const float k0 = gumbel_key(LC.x, u.x, c);                  \
            const float k1 = gumbel_key(LC.y, u.y, c);                  \
            const float k2 = gumbel_key(LC.z, u.z, c);                  \
            const float k3 = gumbel_key(LC.w, u.w, c);                  \
            if (k0 > bv) { bv = k0; bi = base;     }                    \
            if (k1 > bv) { bv = k1; bi = base + 1; }                    \
            if (k2 > bv) { bv = k2; bi = base + 2; }                    \
            if (k3 > bv) { bv = k3; bi = base + 3; }                    \
        }                                                               \
    }

// Greedy path: one async 16B nt load (logits only).
#define ISSUE1(LD, J)                                                   \
    {                                                                   \
        const int fi = min(t + (J) * TPB, last);                        \
        asm volatile("global_load_dwordx4 %0, %1, off nt"               \
                     : "=&v"(LD) : "v"(lg4 + fi));                      \
    }

#define CONS_G(LC, JC)                                                  \
    {                                                                   \
        const int f = t + (JC) * TPB;                                   \
        if (f < V4c) {                                                  \
            const int base = (gbase + f) << 2;                          \
            if (LC.x > bv) { bv = LC.x; bi = base;     }                \
            if (LC.y > bv) { bv = LC.y; bi = base + 1; }                \
            if (LC.z > bv) { bv = LC.z; bi = base + 2; }                \
            if (LC.w > bv) { bv = LC.w; bi = base + 3; }                \
        }                                                               \
    }

__global__ __launch_bounds__(TPB, 8) void sampler_phase1(
    const float* __restrict__ logits,
    const float* __restrict__ temps,
    const float* __restrict__ noise,
    float* __restrict__ ws_val,
    int* __restrict__ ws_idx, int V)
{
    const int chunk = blockIdx.x & (CHUNKS - 1);
    const int b     = blockIdx.x / CHUNKS;
    const int V4    = V >> 2;               // 32064
    const int V4c   = V4 / CHUNKS;          // 4008 (V divisible by 32)
    const int gbase = chunk * V4c;          // this chunk's first float4 index
    const float temp = temps[b];
    const v4f* __restrict__ lg4 =
        (const v4f*)(logits + (size_t)b * V) + gbase;
    const v4f* __restrict__ nz4 =
        (const v4f*)(noise + (size_t)b * V) + gbase;
    const int t    = threadIdx.x;
    const int lane = t & 63;
    const int wave = t >> 6;
    const int last = V4c - 1;
    const int NIT  = (V4c + TPB - 1) / TPB;     // 16 for V=128256
    const int NIT4 = (NIT + 3) & ~3;            // pipeline works in groups of 4

    // Per-wave private 4-stage DMA ring for the noise stream: 16 KiB/block.
    __shared__ v4f nbuf[4][WPB][64];

    float bv = -INFINITY;
    int   bi = 0x7fffffff;

    if (temp == 0.0f) {
        // Greedy: argmax of raw logits, no noise traffic (pure VGPR-nt).
        v4f A0, A1, A2, A3;
        ISSUE1(A0, 0);
        ISSUE1(A1, 1);
        ISSUE1(A2, 2);
        for (int j = 0; j < NIT4; j += 4) {
            ISSUE1(A3, j + 3); WAITV(3); CONS_G(A0, j + 0);
            ISSUE1(A0, j + 4); WAITV(3); CONS_G(A1, j + 1);
            ISSUE1(A1, j + 5); WAITV(3); CONS_G(A2, j + 2);
            ISSUE1(A2, j + 6); WAITV(3); CONS_G(A3, j + 3);
        }
        // Drain; inputs pin buffer registers live until all loads returned.
        asm volatile("s_waitcnt vmcnt(0)"
                     :: "v"(A0), "v"(A1), "v"(A2), "v"(A3) : "memory");
        __builtin_amdgcn_sched_barrier(0);
    } else {
        const float c = (1.0f / temp) * 1.4426950408889634f;  // invT / ln2
        v4f L0, L1, L2, L3;
        ISSUE_H(L0, 0, 0);
        ISSUE_H(L1, 1, 1);
        ISSUE_H(L2, 2, 2);
        for (int j = 0; j < NIT4; j += 4) {
            ISSUE_H(L3, j + 3, 3); WAITV(6); CONS_H(L0, j + 0, 0);
            ISSUE_H(L0, j + 4, 0); WAITV(6); CONS_H(L1, j + 1, 1);
            ISSUE_H(L1, j + 5, 1); WAITV(6); CONS_H(L2, j + 2, 2);
            ISSUE_H(L2, j + 6, 2); WAITV(6); CONS_H(L3, j + 3, 3);
        }
        asm volatile("s_waitcnt vmcnt(0)"
                     :: "v"(L0), "v"(L1), "v"(L2), "v"(L3) : "memory");
        __builtin_amdgcn_sched_barrier(0);
    }

    // wave (64-lane) shuffle reduction, lowest-index tie-break
    #pragma unroll
    for (int off = 32; off > 0; off >>= 1) {
        const float ov = __shfl_down(bv, off);
        const int   oi = __shfl_down(bi, off);
        amax_comb(ov, oi, bv, bi);
    }

    __shared__ float s_v[WPB];
    __shared__ int   s_i[WPB];
    if (lane == 0) { s_v[wave] = bv; s_i[wave] = bi; }
    __syncthreads();
    if (t == 0) {
        #pragma unroll
        for (int w = 1; w < WPB; ++w) amax_comb(s_v[w], s_i[w], bv, bi);
        ws_val[blockIdx.x] = bv;
        ws_idx[blockIdx.x] = bi;
    }
}

__global__ void sampler_phase2(const float* __restrict__ ws_val,
                               const int* __restrict__ ws_idx,
                               int* __restrict__ out, int B)
{
    const int b = blockIdx.x * blockDim.x + threadIdx.x;
    if (b >= B) return;
    float bv = -INFINITY;
    int   bi = 0x7fffffff;
    #pragma unroll
    for (int c = 0; c < CHUNKS; ++c) {
        const float v = ws_val[b * CHUNKS + c];
        const int   i = ws_idx[b * CHUNKS + c];
        // chunk-ascending iteration + strict-> keeps lowest index on ties
        if (v > bv || (v == bv && i < bi)) { bv = v; bi = i; }
    }
    out[b] = bi;
}

extern "C" void kernel_launch(void* const* d_in, const int* in_sizes, int n_in,
                              void* d_out, int out_size, void* d_ws, size_t ws_size,
                              hipStream_t stream) {
    const float* logits = (const float*)d_in[0];   // [B, V] fp32
    const float* temps  = (const float*)d_in[1];   // [B]    fp32
    const float* noise  = (const float*)d_in[2];   // [B, V] fp32
    int* out = (int*)d_out;                        // [B]    int32
    const int B = in_sizes[1];
    const int V = in_sizes[0] / B;

    float* ws_val = (float*)d_ws;                  // [B*CHUNKS]
    int*   ws_idx = (int*)d_ws + (size_t)B * CHUNKS;

    sampler_phase1<<<B * CHUNKS, TPB, 0, stream>>>(logits, temps, noise,
                                                   ws_val, ws_idx, V);
    sampler_phase2<<<(B + 255) / 256, 256, 0, stream>>>(ws_val, ws_idx, out, B);
}